// Round 2
// baseline (1002.526 us; speedup 1.0000x reference)
//
#include <hip/hip_runtime.h>
#include <cstdint>
#include <cstddef>

// Conv2d 3x3 s1 p1: N=16, CI=64, CO=128, H=W=224, fp32 in/out.
// v2: pre-pass packs x -> bf16 xp[n][hp(226)][cb(8)][wp(226)][8ci] with zeroed
// halos; main kernel stages via global_load_lds (16B DMA) into LDS and runs
// implicit-GEMM bf16 MFMA. Fallback to v1 path if ws_size too small.

typedef short bf16x8 __attribute__((ext_vector_type(8)));
typedef float f32x4 __attribute__((ext_vector_type(4)));

#define N_ 16
#define CI_ 64
#define CO_ 128
#define H_ 224
#define W_ 224
#define HW_ (H_ * W_)

// xp strides in shorts
#define WP_ 226
#define CBS_ 1808ULL        // WP_*8
#define HPS_ 14464ULL       // 8*CBS_
#define NS_ 3268864ULL      // 226*HPS_

__device__ __forceinline__ unsigned short f2bf(float f) {
    unsigned u = __builtin_bit_cast(unsigned, f);
    u += 0x7FFFu + ((u >> 16) & 1u);   // round-to-nearest-even
    return (unsigned short)(u >> 16);
}

// weight [CO][CI][3][3] fp32 -> wr[t][co][ci] bf16  (t = kh*3+kw)
__global__ void prep_weight(const float* __restrict__ w, unsigned short* __restrict__ wr) {
    int i = blockIdx.x * 256 + threadIdx.x;          // i = t*8192 + co*64 + ci
    if (i >= 9 * CO_ * CI_) return;
    int ci = i & 63;
    int co = (i >> 6) & 127;
    int t  = i >> 13;
    wr[i] = f2bf(w[(co * CI_ + ci) * 9 + t]);
}

// x[n][ci][h][w] fp32 -> xp[n][hp][cb][wp][c8] bf16, halos (hp 0/225, wp 0/225) zero.
__global__ __launch_bounds__(256) void prep_x(const float* __restrict__ x,
                                              unsigned short* __restrict__ xp) {
    int b = blockIdx.x;                 // 16*226
    int n = b / 226, hp = b - n * 226;
    int tid = threadIdx.x;
    unsigned short* row = xp + (size_t)n * NS_ + (size_t)hp * HPS_;
    if (hp == 0 || hp == 225) {
        #pragma unroll
        for (int k = 0; k < 8; ++k) {
            int i = k * 256 + tid;
            if (i < 1808) ((uint4*)row)[i] = make_uint4(0, 0, 0, 0);
        }
        return;
    }
    int h = hp - 1;
    const float* xb = x + (size_t)n * CI_ * HW_ + (size_t)h * W_;
    for (int k = 0; k < 7; ++k) {
        int item = k * 256 + tid;       // 1792 = 8cb * 224w
        int w = item % 224;
        int cb = item / 224;
        unsigned r[4];
        #pragma unroll
        for (int c = 0; c < 4; ++c) {
            float lo = xb[(size_t)(cb * 8 + 2 * c) * HW_ + w];
            float hi = xb[(size_t)(cb * 8 + 2 * c + 1) * HW_ + w];
            r[c] = (unsigned)f2bf(lo) | ((unsigned)f2bf(hi) << 16);
        }
        *(uint4*)(row + (size_t)cb * CBS_ + (size_t)(w + 1) * 8) = make_uint4(r[0], r[1], r[2], r[3]);
    }
    if (tid < 16) {
        int cb = tid >> 1, wp = (tid & 1) * 225;
        *(uint4*)(row + (size_t)cb * CBS_ + (size_t)wp * 8) = make_uint4(0, 0, 0, 0);
    }
}

// Main: one WG (512 thr, 8 waves) -> out[n][0:128][h0:h0+2][0:224].
__global__ __launch_bounds__(512, 4) void conv2(
    const unsigned short* __restrict__ xp, const unsigned short* __restrict__ wr,
    const float* __restrict__ bias, float* __restrict__ out)
{
    // xs[r(4)][cbl(4)][wp(226)][8 ci] bf16 = 57,856 B
    __shared__ __align__(16) unsigned short xs[4 * 4 * 226 * 8];

    int bid = blockIdx.x;
    int swz = (bid & 7) * 224 + (bid >> 3);    // bijective: 1792 = 8*224
    int n = swz / 112;
    int hblk = swz - n * 112;
    int h0 = hblk * 2;

    int tid = threadIdx.x, lane = tid & 63, wid = tid >> 6;
    int hr = wid & 1, nh = (wid >> 1) & 1, mh = wid >> 2;
    int lrow = lane & 15, lk = lane >> 4;

    f32x4 acc[4][7];
    #pragma unroll
    for (int a = 0; a < 4; ++a)
        #pragma unroll
        for (int b2 = 0; b2 < 7; ++b2)
            #pragma unroll
            for (int k = 0; k < 4; ++k)
                acc[a][b2][k] = 0.0f;

    const unsigned short* xpn = xp + (size_t)n * NS_;

    for (int ch = 0; ch < 2; ++ch) {
        if (ch) __syncthreads();
        // ---- stage via global_load_lds: 16 runs of 226 x 16B, linear LDS ----
        #pragma unroll
        for (int rr = 0; rr < 2; ++rr) {
            int run = wid * 2 + rr;            // 0..15
            int r = run >> 2, cbl = run & 3;
            const unsigned short* src = xpn + (size_t)(h0 + r) * HPS_ + (size_t)(ch * 4 + cbl) * CBS_;
            unsigned short* dst = &xs[(size_t)(r * 4 + cbl) * (226 * 8)];
            #pragma unroll
            for (int c = 0; c < 4; ++c) {
                int chunk = c * 64 + lane;
                if (chunk < 226)
                    __builtin_amdgcn_global_load_lds(
                        (const __attribute__((address_space(1))) void*)(src + (size_t)chunk * 8),
                        (__attribute__((address_space(3))) void*)(dst + c * 512),
                        16, 0, 0);
            }
        }
        __syncthreads();   // compiler drains vmcnt(0) before s_barrier

        // ---- 9 taps x K=32 ----
        #pragma unroll
        for (int t = 0; t < 9; ++t) {
            int kh = t / 3, kw = t - kh * 3;
            bf16x8 afr[4];
            #pragma unroll
            for (int mf = 0; mf < 4; ++mf) {
                size_t ai = ((size_t)(t * 128 + mh * 64 + mf * 16 + lrow)) * 64
                          + (size_t)(ch * 32 + lk * 8);
                afr[mf] = *(const bf16x8*)(wr + ai);
            }
            int rbase = ((hr + kh) * 4 + lk) * 226;
            int wpb = nh * 112 + lrow + kw;
            #pragma unroll
            for (int nf = 0; nf < 7; ++nf) {
                bf16x8 bfr = *(const bf16x8*)(&xs[(size_t)(rbase + wpb + nf * 16) * 8]);
                #pragma unroll
                for (int mf = 0; mf < 4; ++mf)
                    acc[mf][nf] = __builtin_amdgcn_mfma_f32_16x16x32_bf16(
                        afr[mf], bfr, acc[mf][nf], 0, 0, 0);
            }
        }
    }

    // ---- epilogue: bias + nontemporal store (64B/instr coalesced) ----
    int h = h0 + hr;
    #pragma unroll
    for (int mf = 0; mf < 4; ++mf) {
        #pragma unroll
        for (int r = 0; r < 4; ++r) {
            int co = mh * 64 + mf * 16 + lk * 4 + r;
            float bv = bias[co];
            size_t ob = (((size_t)n * CO_ + co) * H_ + h) * W_ + nh * 112 + lrow;
            #pragma unroll
            for (int nf = 0; nf < 7; ++nf)
                __builtin_nontemporal_store(acc[mf][nf][r] + bv, out + ob + (size_t)nf * 16);
        }
    }
}

// ---------------- round-1 fallback (used only if ws_size is small) ----------------
__global__ __launch_bounds__(512, 2) void conv_mfma(
    const float* __restrict__ x, const unsigned short* __restrict__ wr,
    const float* __restrict__ bias, float* __restrict__ out)
{
    __shared__ unsigned short xs[4 * 4 * 226 * 8];
    int bid = blockIdx.x;
    int swz = (bid & 7) * 224 + (bid >> 3);
    int n = swz / 112;
    int hblk = swz - n * 112;
    int h0 = hblk * 2;
    int tid = threadIdx.x;
    int lane = tid & 63;
    int wid = tid >> 6;
    int hr = wid & 1, nh = (wid >> 1) & 1, mh = wid >> 2;
    int lrow = lane & 15, lk = lane >> 4;

    f32x4 acc[4][7];
    #pragma unroll
    for (int a = 0; a < 4; ++a)
        #pragma unroll
        for (int b = 0; b < 7; ++b)
            #pragma unroll
            for (int k = 0; k < 4; ++k)
                acc[a][b][k] = 0.0f;

    for (int ch = 0; ch < 2; ++ch) {
        if (ch) __syncthreads();
        const float* xb = x + ((size_t)n * CI_ + (size_t)ch * 32) * HW_;
        int wcol = tid % 224;
        int rem = tid / 224;
        for (int it = 0; it < 7; ++it) {
            float v[8]; int bi[8];
            #pragma unroll
            for (int u = 0; u < 8; ++u) {
                int ciL = rem & 31;
                int r4 = rem >> 5;
                int hh = h0 - 1 + r4;
                float val = 0.0f;
                if ((unsigned)hh < (unsigned)H_)
                    val = xb[(size_t)ciL * HW_ + (size_t)hh * W_ + wcol];
                v[u] = val;
                bi[u] = (((r4 << 2) + (ciL >> 3)) * 226 + wcol + 1) * 8 + (ciL & 7);
                wcol += 64; rem += 2;
                if (wcol >= 224) { wcol -= 224; rem += 1; }
            }
            #pragma unroll
            for (int u = 0; u < 8; ++u)
                xs[bi[u]] = f2bf(v[u]);
        }
        if (tid < 256) {
            int wp = (tid & 1) * 225;
            int ciL = (tid >> 1) & 31;
            int r4 = tid >> 6;
            xs[(((r4 << 2) + (ciL >> 3)) * 226 + wp) * 8 + (ciL & 7)] = 0;
        }
        __syncthreads();

        #pragma unroll
        for (int t = 0; t < 9; ++t) {
            int kh = t / 3, kw = t - kh * 3;
            bf16x8 afr[4];
            #pragma unroll
            for (int mf = 0; mf < 4; ++mf) {
                size_t ai = ((size_t)(t * 128 + mh * 64 + mf * 16 + lrow)) * 64
                          + (size_t)(ch * 32 + lk * 8);
                afr[mf] = *(const bf16x8*)(wr + ai);
            }
            int rbase = ((hr + kh) * 4 + lk) * 226;
            int wpb = nh * 112 + lrow + kw;
            #pragma unroll
            for (int nf = 0; nf < 7; ++nf) {
                bf16x8 bfr = *(const bf16x8*)(&xs[(size_t)(rbase + wpb + nf * 16) * 8]);
                #pragma unroll
                for (int mf = 0; mf < 4; ++mf)
                    acc[mf][nf] = __builtin_amdgcn_mfma_f32_16x16x32_bf16(
                        afr[mf], bfr, acc[mf][nf], 0, 0, 0);
            }
        }
    }

    int h = h0 + hr;
    #pragma unroll
    for (int mf = 0; mf < 4; ++mf) {
        #pragma unroll
        for (int r = 0; r < 4; ++r) {
            int co = mh * 64 + mf * 16 + lk * 4 + r;
            float bv = bias[co];
            size_t ob = (((size_t)n * CO_ + co) * H_ + h) * W_ + nh * 112 + lrow;
            #pragma unroll
            for (int nf = 0; nf < 7; ++nf)
                out[ob + (size_t)nf * 16] = acc[mf][nf][r] + bv;
        }
    }
}

extern "C" void kernel_launch(void* const* d_in, const int* in_sizes, int n_in,
                              void* d_out, int out_size, void* d_ws, size_t ws_size,
                              hipStream_t stream) {
    const float* x    = (const float*)d_in[0];
    const float* w    = (const float*)d_in[1];
    const float* bias = (const float*)d_in[2];
    float* out = (float*)d_out;
    unsigned short* wr = (unsigned short*)d_ws;          // 147,456 B
    const size_t xp_bytes = (size_t)N_ * NS_ * 2;        // 104,603,648 B
    const size_t need = 147456 + xp_bytes;

    prep_weight<<<dim3(288), dim3(256), 0, stream>>>(w, wr);
    if (ws_size >= need) {
        unsigned short* xp = wr + 73728;                 // +147,456 B
        prep_x<<<dim3(16 * 226), dim3(256), 0, stream>>>(x, xp);
        conv2<<<dim3(16 * 112), dim3(512), 0, stream>>>(xp, wr, bias, out);
    } else {
        conv_mfma<<<dim3(16 * 112), dim3(512), 0, stream>>>(x, wr, bias, out);
    }
}